// Round 2
// baseline (140.464 us; speedup 1.0000x reference)
//
#include <hip/hip_runtime.h>
#include <stdint.h>

#define BB 8
#define C  64
#define H  256
#define W  256
#define HW (H*W)
#define EPSV 1e-6f

// ---------------- K1: fused sign-pack + per-block stats partials ----------------
// grid: 512 blocks (b = blk>>6, 4-row group = blk&63), 256 threads
__global__ __launch_bounds__(256) void k_pack_stats(
    const float* __restrict__ x,
    const float* __restrict__ bmove,
    unsigned long long* __restrict__ packed,
    float* __restrict__ part /* [512 bc][3 st][64 rg] */) {
  int blk = blockIdx.x;
  int b  = blk >> 6;
  int rg = blk & 63;
  int tid = threadIdx.x;
  int h  = (rg << 2) + (tid >> 6);
  int w0 = (tid & 63) << 2;
  int wid = tid >> 6, lane = tid & 63;

  __shared__ float sred[4][64][3];
  for (int i = tid; i < 4 * 64 * 3; i += 256) ((float*)sred)[i] = 0.f;
  __syncthreads();

  const float* px = x + (size_t)b * C * HW + h * W + w0;
  unsigned long long wd0 = 0, wd1 = 0, wd2 = 0, wd3 = 0;
  for (int c = 0; c < 64; c++) {
    float4 v = *(const float4*)(px + (size_t)c * HW);
    float bm = bmove[c];
    float a0 = v.x + bm, a1 = v.y + bm, a2 = v.z + bm, a3 = v.w + bm;
    unsigned long long bit = 1ull << c;
    if (a0 > 0.f) wd0 |= bit;
    if (a1 > 0.f) wd1 |= bit;
    if (a2 > 0.f) wd2 |= bit;
    if (a3 > 0.f) wd3 |= bit;
    float s  = a0 + a1 + a2 + a3;
    float s2 = a0*a0 + a1*a1 + a2*a2 + a3*a3;
    float sa = fabsf(a0) + fabsf(a1) + fabsf(a2) + fabsf(a3);
    #pragma unroll
    for (int off = 32; off > 0; off >>= 1) {
      s  += __shfl_down(s,  off, 64);
      s2 += __shfl_down(s2, off, 64);
      sa += __shfl_down(sa, off, 64);
    }
    if (lane == 0) {
      sred[wid][c][0] += s;
      sred[wid][c][1] += s2;
      sred[wid][c][2] += sa;
    }
  }
  unsigned long long* dst = packed + (size_t)(b * H + h) * W + w0;
  dst[0] = wd0; dst[1] = wd1; dst[2] = wd2; dst[3] = wd3;
  __syncthreads();
  if (tid < 192) {
    int c = tid / 3, st = tid - c * 3;
    float v = sred[0][c][st] + sred[1][c][st] + sred[2][c][st] + sred[3][c][st];
    part[((size_t)(b * 64 + c) * 3 + st) * 64 + rg] = v;
  }
}

// ---------------- K2: finish stats, gate (conv1d over C + sigmoid), weight prep
__global__ __launch_bounds__(512) void k_gate(
    const float* __restrict__ part,
    const float* __restrict__ w_conv,
    const float* __restrict__ w1d,
    float* __restrict__ alpha,
    unsigned long long* __restrict__ wsign) {
  __shared__ float stA[512], stM[512], stS[512];  // [b*64 + c]
  __shared__ float swv[64];
  int tid = threadIdx.x;
  {
    const float* p = part + (size_t)tid * 192;
    float s = 0.f, s2 = 0.f, sa = 0.f;
    for (int k = 0; k < 64; k++) { s += p[k]; s2 += p[64 + k]; sa += p[128 + k]; }
    const float invN = 1.f / (float)HW;
    float mean = s * invN;
    float var  = (s2 - s * s * invN) * (1.f / (float)(HW - 1)) + EPSV;
    stA[tid] = sa * invN;
    stM[tid] = mean;
    stS[tid] = sqrtf(var);
  }
  {
    int o = tid >> 3, g = tid & 7;                 // 8 lanes per out-channel
    const float* wo = w_conv + o * 576 + g * 72;   // 8 in-channels x 9 taps
    float s = 0.f;
    unsigned long long wb[9] = {0,0,0,0,0,0,0,0,0};
    #pragma unroll
    for (int i = 0; i < 8; i++) {
      #pragma unroll
      for (int t = 0; t < 9; t++) {
        float v = wo[i * 9 + t];
        s += fabsf(v);
        if (v > 0.f) wb[t] |= (1ull << (g * 8 + i));
      }
    }
    #pragma unroll
    for (int off = 4; off > 0; off >>= 1) {
      s += __shfl_down(s, off, 8);
      #pragma unroll
      for (int t = 0; t < 9; t++)
        wb[t] |= __shfl_down(wb[t], off, 8);
    }
    if (g == 0) {
      swv[o] = s * (1.f / 576.f);
      #pragma unroll
      for (int t = 0; t < 9; t++) wsign[o * 9 + t] = wb[t];
    }
  }
  __syncthreads();
  int b = tid >> 6, c = tid & 63;
  float y = 0.f;
  #pragma unroll
  for (int k = 0; k < 3; k++) {
    int cc = c + k - 1;
    if (cc >= 0 && cc < 64) {
      int j = b * 64 + cc;
      y += stA[j] * w1d[0 * 3 + k] + stM[j] * w1d[1 * 3 + k] + stS[j] * w1d[2 * 3 + k];
    }
  }
  float gate = 1.f / (1.f + expf(-y));
  alpha[tid] = gate * swv[c];   // folds scale_w[o] * gate[b][o]
}

// ---------------- K3: XNOR conv + scale + rprelu + residual ----------------
__global__ __launch_bounds__(256) void k_conv(const unsigned long long* __restrict__ packed,
                                              const unsigned long long* __restrict__ wsign,
                                              const float* __restrict__ alpha,
                                              const float* __restrict__ x,
                                              const float* __restrict__ pr_b0,
                                              const float* __restrict__ prelu_a,
                                              const float* __restrict__ pr_b1,
                                              float* __restrict__ out) {
  int bh = blockIdx.x;            // b*256 + h
  int b = bh >> 8, h = bh & 255;
  int w = threadIdx.x;
  __shared__ unsigned long long rows[3][W];
  bool r0v = (h > 0), r2v = (h < H - 1);
  const unsigned long long* pb = packed + (size_t)b * HW;
  rows[1][w] = pb[h * W + w];
  if (r0v) rows[0][w] = pb[(h - 1) * W + w];
  if (r2v) rows[2][w] = pb[(h + 1) * W + w];
  __syncthreads();

  bool lv = (w > 0), rv = (w < W - 1);
  unsigned long long vmL = lv ? ~0ull : 0ull;
  unsigned long long vmR = rv ? ~0ull : 0ull;
  unsigned long long nL[3], nC[3], nR[3];
  #pragma unroll
  for (int r = 0; r < 3; r++) {
    nC[r] = rows[r][w];
    nL[r] = rows[r][lv ? w - 1 : w];
    nR[r] = rows[r][rv ? w + 1 : w];
  }
  int nrows = 1 + (int)r0v + (int)r2v;
  int ncols = 1 + (int)lv + (int)rv;
  float base = 64.f * (float)(nrows * ncols);
  size_t xoff = (size_t)b * C * HW + h * W + w;

  for (int o = 0; o < 64; o++) {
    const unsigned long long* wso = wsign + o * 9;
    int cnt = 0;
    if (r0v) {
      cnt += __popcll((nL[0] ^ wso[0]) & vmL);
      cnt += __popcll( nC[0] ^ wso[1]);
      cnt += __popcll((nR[0] ^ wso[2]) & vmR);
    }
    cnt += __popcll((nL[1] ^ wso[3]) & vmL);
    cnt += __popcll( nC[1] ^ wso[4]);
    cnt += __popcll((nR[1] ^ wso[5]) & vmR);
    if (r2v) {
      cnt += __popcll((nL[2] ^ wso[6]) & vmL);
      cnt += __popcll( nC[2] ^ wso[7]);
      cnt += __popcll((nR[2] ^ wso[8]) & vmR);
    }
    float dot = base - 2.f * (float)cnt;
    float v = dot * alpha[b * 64 + o];
    float y = v + pr_b0[o];
    y = (y > 0.f) ? y : prelu_a[o] * y;
    y += pr_b1[o];
    size_t idx = xoff + (size_t)o * HW;
    __builtin_nontemporal_store(y + x[idx], &out[idx]);
  }
}

extern "C" void kernel_launch(void* const* d_in, const int* in_sizes, int n_in,
                              void* d_out, int out_size, void* d_ws, size_t ws_size,
                              hipStream_t stream) {
  const float* x       = (const float*)d_in[0];
  const float* b_move  = (const float*)d_in[1];
  const float* w_conv  = (const float*)d_in[2];
  const float* w1d     = (const float*)d_in[3];
  const float* pr_b0   = (const float*)d_in[4];
  const float* prelu_a = (const float*)d_in[5];
  const float* pr_b1   = (const float*)d_in[6];
  float* out = (float*)d_out;

  char* ws = (char*)d_ws;
  // ws layout: packed u64[8*256*256] = 4 MiB; part = 512*3*64 f32 (384 KiB);
  // alpha (512 f32); wsign (64*9 u64)
  unsigned long long* packed = (unsigned long long*)ws;
  float* part  = (float*)(ws + 4194304);
  float* alpha = (float*)(ws + 4194304 + 393216);
  unsigned long long* wsign = (unsigned long long*)(ws + 4194304 + 393216 + 4096);

  k_pack_stats<<<512, 256, 0, stream>>>(x, b_move, packed, part);
  k_gate<<<1, 512, 0, stream>>>(part, w_conv, w1d, alpha, wsign);
  k_conv<<<BB * H, 256, 0, stream>>>(packed, wsign, alpha, x,
                                     pr_b0, prelu_a, pr_b1, out);
}

// Round 3
// 128.693 us; speedup vs baseline: 1.0915x; 1.0915x over previous
//
#include <hip/hip_runtime.h>
#include <stdint.h>

#define BB 8
#define C  64
#define H  256
#define W  256
#define HW (H*W)
#define EPSV 1e-6f

// ---------------- K1: fused transpose + stats + ballot-pack ----------------
// 1024 blocks (b = blk>>7, 2-row strip rg = blk&127), 256 threads.
// Per tile (64ch x 128px): coalesced load -> LDS(transposed view) ->
// lane=channel consume: register stats accumulate + __ballot sign-pack.
__global__ __launch_bounds__(256) void k_pack_stats(
    const float* __restrict__ x,
    const float* __restrict__ bmove,
    unsigned long long* __restrict__ packed,
    float* __restrict__ part /* [512 bc][3 st][128 rg] */) {
  int blk = blockIdx.x;
  int b   = blk >> 7;
  int rg  = blk & 127;
  int h0  = rg << 1;
  int tid = threadIdx.x;
  int wid = tid >> 6, lane = tid & 63;

  __shared__ float4 lds4[64 * 33];      // [c][33 f4] padded: conflict-free R/W
  __shared__ float fred[4][3][64];

  float bm = bmove[lane];               // lane = channel in consume phase
  float s = 0.f, s2 = 0.f, sa = 0.f;

  int p4l = tid & 31;                   // load phase: f4 index within 128px
  int cg  = tid >> 5;                   // load phase: channel sub-group 0..7
  const size_t bbase = (size_t)b * C * HW;

  for (int tile = 0; tile < 4; ++tile) {
    int h  = h0 + (tile >> 1);
    int wb = (tile & 1) << 7;           // 0 or 128
    __syncthreads();
    #pragma unroll
    for (int cc = 0; cc < 8; ++cc) {
      int c = cg + (cc << 3);
      const float4* src = (const float4*)(x + bbase + (size_t)c * HW + h * W + wb) + p4l;
      lds4[c * 33 + p4l] = *src;
    }
    __syncthreads();
    unsigned long long* pdst = packed + ((size_t)(b * H + h)) * W + wb;
    #pragma unroll
    for (int k = 0; k < 8; ++k) {
      int p4i = (wid << 3) + k;         // this wave's pixel quarter
      float4 v = lds4[lane * 33 + p4i];
      float a0 = v.x + bm, a1 = v.y + bm, a2 = v.z + bm, a3 = v.w + bm;
      s  += a0 + a1 + a2 + a3;
      s2 += a0*a0 + a1*a1 + a2*a2 + a3*a3;
      sa += fabsf(a0) + fabsf(a1) + fabsf(a2) + fabsf(a3);
      unsigned long long q0 = __ballot(a0 > 0.f);
      unsigned long long q1 = __ballot(a1 > 0.f);
      unsigned long long q2 = __ballot(a2 > 0.f);
      unsigned long long q3 = __ballot(a3 > 0.f);
      unsigned long long qq = (lane == 0) ? q0 : (lane == 1) ? q1
                            : (lane == 2) ? q2 : q3;
      if (lane < 4) pdst[(p4i << 2) + lane] = qq;   // 32B coalesced store
    }
  }
  fred[wid][0][lane] = s;
  fred[wid][1][lane] = s2;
  fred[wid][2][lane] = sa;
  __syncthreads();
  if (tid < 192) {
    int st = tid >> 6, c = tid & 63;
    float v = fred[0][st][c] + fred[1][st][c] + fred[2][st][c] + fred[3][st][c];
    part[((size_t)(b * 64 + c) * 3 + st) * 128 + rg] = v;
  }
}

// ---------------- K2: finish stats, gate (conv1d over C + sigmoid), weight prep
__global__ __launch_bounds__(512) void k_gate(
    const float* __restrict__ part,
    const float* __restrict__ w_conv,
    const float* __restrict__ w1d,
    float* __restrict__ alpha,
    unsigned long long* __restrict__ wsign) {
  __shared__ float stA[512], stM[512], stS[512];  // [b*64 + c]
  __shared__ float swv[64];
  int tid = threadIdx.x;
  {
    const float4* p = (const float4*)(part + (size_t)tid * 384);
    float s = 0.f, s2 = 0.f, sa = 0.f;
    for (int k = 0;  k < 32; k++) { float4 v = p[k]; s  += v.x + v.y + v.z + v.w; }
    for (int k = 32; k < 64; k++) { float4 v = p[k]; s2 += v.x + v.y + v.z + v.w; }
    for (int k = 64; k < 96; k++) { float4 v = p[k]; sa += v.x + v.y + v.z + v.w; }
    const float invN = 1.f / (float)HW;
    float mean = s * invN;
    float var  = (s2 - s * s * invN) * (1.f / (float)(HW - 1)) + EPSV;
    stA[tid] = sa * invN;
    stM[tid] = mean;
    stS[tid] = sqrtf(var);
  }
  {
    int o = tid >> 3, g = tid & 7;                 // 8 lanes per out-channel
    const float* wo = w_conv + o * 576 + g * 72;   // 8 in-channels x 9 taps
    float s = 0.f;
    unsigned long long wb[9] = {0,0,0,0,0,0,0,0,0};
    #pragma unroll
    for (int i = 0; i < 8; i++) {
      #pragma unroll
      for (int t = 0; t < 9; t++) {
        float v = wo[i * 9 + t];
        s += fabsf(v);
        if (v > 0.f) wb[t] |= (1ull << (g * 8 + i));
      }
    }
    #pragma unroll
    for (int off = 4; off > 0; off >>= 1) {
      s += __shfl_down(s, off, 8);
      #pragma unroll
      for (int t = 0; t < 9; t++)
        wb[t] |= __shfl_down(wb[t], off, 8);
    }
    if (g == 0) {
      swv[o] = s * (1.f / 576.f);
      #pragma unroll
      for (int t = 0; t < 9; t++) wsign[o * 9 + t] = wb[t];
    }
  }
  __syncthreads();
  int b = tid >> 6, c = tid & 63;
  float y = 0.f;
  #pragma unroll
  for (int k = 0; k < 3; k++) {
    int cc = c + k - 1;
    if (cc >= 0 && cc < 64) {
      int j = b * 64 + cc;
      y += stA[j] * w1d[0 * 3 + k] + stM[j] * w1d[1 * 3 + k] + stS[j] * w1d[2 * 3 + k];
    }
  }
  float gate = 1.f / (1.f + expf(-y));
  alpha[tid] = gate * swv[c];   // folds scale_w[o] * gate[b][o]
}

// ---------------- K3: XNOR conv + scale + rprelu + residual ----------------
__global__ __launch_bounds__(256) void k_conv(const unsigned long long* __restrict__ packed,
                                              const unsigned long long* __restrict__ wsign,
                                              const float* __restrict__ alpha,
                                              const float* __restrict__ x,
                                              const float* __restrict__ pr_b0,
                                              const float* __restrict__ prelu_a,
                                              const float* __restrict__ pr_b1,
                                              float* __restrict__ out) {
  int bh = blockIdx.x;            // b*256 + h
  int b = bh >> 8, h = bh & 255;
  int w = threadIdx.x;
  __shared__ unsigned long long rows[3][W];
  bool r0v = (h > 0), r2v = (h < H - 1);
  const unsigned long long* pb = packed + (size_t)b * HW;
  rows[1][w] = pb[h * W + w];
  if (r0v) rows[0][w] = pb[(h - 1) * W + w];
  if (r2v) rows[2][w] = pb[(h + 1) * W + w];
  __syncthreads();

  bool lv = (w > 0), rv = (w < W - 1);
  unsigned long long vmL = lv ? ~0ull : 0ull;
  unsigned long long vmR = rv ? ~0ull : 0ull;
  unsigned long long nL[3], nC[3], nR[3];
  #pragma unroll
  for (int r = 0; r < 3; r++) {
    nC[r] = rows[r][w];
    nL[r] = rows[r][lv ? w - 1 : w];
    nR[r] = rows[r][rv ? w + 1 : w];
  }
  int nrows = 1 + (int)r0v + (int)r2v;
  int ncols = 1 + (int)lv + (int)rv;
  float base = 64.f * (float)(nrows * ncols);
  size_t xoff = (size_t)b * C * HW + h * W + w;

  for (int o = 0; o < 64; o++) {
    const unsigned long long* wso = wsign + o * 9;
    int cnt = 0;
    if (r0v) {
      cnt += __popcll((nL[0] ^ wso[0]) & vmL);
      cnt += __popcll( nC[0] ^ wso[1]);
      cnt += __popcll((nR[0] ^ wso[2]) & vmR);
    }
    cnt += __popcll((nL[1] ^ wso[3]) & vmL);
    cnt += __popcll( nC[1] ^ wso[4]);
    cnt += __popcll((nR[1] ^ wso[5]) & vmR);
    if (r2v) {
      cnt += __popcll((nL[2] ^ wso[6]) & vmL);
      cnt += __popcll( nC[2] ^ wso[7]);
      cnt += __popcll((nR[2] ^ wso[8]) & vmR);
    }
    float dot = base - 2.f * (float)cnt;
    float v = dot * alpha[b * 64 + o];
    float y = v + pr_b0[o];
    y = (y > 0.f) ? y : prelu_a[o] * y;
    y += pr_b1[o];
    size_t idx = xoff + (size_t)o * HW;
    __builtin_nontemporal_store(y + x[idx], &out[idx]);
  }
}

extern "C" void kernel_launch(void* const* d_in, const int* in_sizes, int n_in,
                              void* d_out, int out_size, void* d_ws, size_t ws_size,
                              hipStream_t stream) {
  const float* x       = (const float*)d_in[0];
  const float* b_move  = (const float*)d_in[1];
  const float* w_conv  = (const float*)d_in[2];
  const float* w1d     = (const float*)d_in[3];
  const float* pr_b0   = (const float*)d_in[4];
  const float* prelu_a = (const float*)d_in[5];
  const float* pr_b1   = (const float*)d_in[6];
  float* out = (float*)d_out;

  char* ws = (char*)d_ws;
  // ws: packed u64[8*256*256] = 4 MiB; part = 512*3*128 f32 (768 KiB);
  // alpha (512 f32); wsign (64*9 u64)
  unsigned long long* packed = (unsigned long long*)ws;
  float* part  = (float*)(ws + 4194304);
  float* alpha = (float*)(ws + 4194304 + 786432);
  unsigned long long* wsign = (unsigned long long*)(ws + 4194304 + 786432 + 2048);

  k_pack_stats<<<1024, 256, 0, stream>>>(x, b_move, packed, part);
  k_gate<<<1, 512, 0, stream>>>(part, w_conv, w1d, alpha, wsign);
  k_conv<<<BB * H, 256, 0, stream>>>(packed, wsign, alpha, x,
                                     pr_b0, prelu_a, pr_b1, out);
}

// Round 5
// 120.507 us; speedup vs baseline: 1.1656x; 1.0679x over previous
//
#include <hip/hip_runtime.h>
#include <stdint.h>

#define BB 8
#define C  64
#define H  256
#define W  256
#define HW (H*W)
#define EPSV 1e-6f

typedef unsigned long long u64;
typedef float __attribute__((ext_vector_type(4))) f32x4;

// ---------------- K1a: per-(b,c) stats, pure streaming ----------------
// 512 blocks = one per (b,c) plane. Register accumulation, one reduce at end.
__global__ __launch_bounds__(256) void k_stats(const float* __restrict__ x,
                                               const float* __restrict__ bmove,
                                               float* __restrict__ sums /* [3][512] */) {
  int bc = blockIdx.x;
  float bm = bmove[bc & 63];
  const f32x4* p = (const f32x4*)(x + (size_t)bc * HW);
  int t = threadIdx.x;
  float s = 0.f, s2 = 0.f, sa = 0.f;
  #pragma unroll 8
  for (int k = 0; k < 64; ++k) {
    f32x4 v = p[(k << 8) | t];
    float a0 = v.x + bm, a1 = v.y + bm, a2 = v.z + bm, a3 = v.w + bm;
    s  += a0 + a1 + a2 + a3;
    s2 += a0*a0 + a1*a1 + a2*a2 + a3*a3;
    sa += fabsf(a0) + fabsf(a1) + fabsf(a2) + fabsf(a3);
  }
  #pragma unroll
  for (int off = 32; off > 0; off >>= 1) {
    s  += __shfl_down(s,  off, 64);
    s2 += __shfl_down(s2, off, 64);
    sa += __shfl_down(sa, off, 64);
  }
  __shared__ float red[4][3];
  int wid = t >> 6;
  if ((t & 63) == 0) { red[wid][0] = s; red[wid][1] = s2; red[wid][2] = sa; }
  __syncthreads();
  if (t == 0) {
    float S  = red[0][0] + red[1][0] + red[2][0] + red[3][0];
    float S2 = red[0][1] + red[1][1] + red[2][1] + red[3][1];
    float SA = red[0][2] + red[1][2] + red[2][2] + red[3][2];
    sums[bc] = S; sums[512 + bc] = S2; sums[1024 + bc] = SA;
  }
}

// ---------------- K1b: LDS-transpose + ballot sign-pack ----------------
// 1024 blocks (b = blk>>7, 2-row strip), 256 threads.
__global__ __launch_bounds__(256) void k_pack(const float* __restrict__ x,
                                              const float* __restrict__ bmove,
                                              u64* __restrict__ packed) {
  int blk = blockIdx.x;
  int b   = blk >> 7;
  int rg  = blk & 127;
  int h0  = rg << 1;
  int tid = threadIdx.x;
  int wid = tid >> 6, lane = tid & 63;
  __shared__ f32x4 lds4[64 * 33];

  float bm = bmove[lane];               // lane = channel in consume phase
  int p4l = tid & 31;
  int cg  = tid >> 5;
  const size_t bbase = (size_t)b * C * HW;

  for (int tile = 0; tile < 4; ++tile) {
    int h  = h0 + (tile >> 1);
    int wb = (tile & 1) << 7;
    __syncthreads();
    #pragma unroll
    for (int cc = 0; cc < 8; ++cc) {
      int c = cg + (cc << 3);
      lds4[c * 33 + p4l] =
          *((const f32x4*)(x + bbase + (size_t)c * HW + h * W + wb) + p4l);
    }
    __syncthreads();
    u64* pdst = packed + ((size_t)(b * H + h)) * W + wb;
    #pragma unroll
    for (int k = 0; k < 8; ++k) {
      int p4i = (wid << 3) + k;
      f32x4 v = lds4[lane * 33 + p4i];
      u64 q0 = __ballot(v.x + bm > 0.f);
      u64 q1 = __ballot(v.y + bm > 0.f);
      u64 q2 = __ballot(v.z + bm > 0.f);
      u64 q3 = __ballot(v.w + bm > 0.f);
      u64 qa = (lane & 1) ? q1 : q0;
      u64 qb = (lane & 1) ? q3 : q2;
      u64 qq = (lane & 2) ? qb : qa;
      if (lane < 4) pdst[(p4i << 2) + lane] = qq;
    }
  }
}

// ---------------- K2: gate (conv1d over C + sigmoid) + weight prep ----------
__global__ __launch_bounds__(512) void k_gate(const float* __restrict__ sums,
                                              const float* __restrict__ w_conv,
                                              const float* __restrict__ w1d,
                                              float* __restrict__ alpha,
                                              u64* __restrict__ wsign) {
  __shared__ float stA[512], stM[512], stS[512];  // [b*64 + c]
  __shared__ float swv[64];
  int tid = threadIdx.x;
  {
    float s = sums[tid], s2 = sums[512 + tid], sa = sums[1024 + tid];
    const float invN = 1.f / (float)HW;
    float mean = s * invN;
    float var  = (s2 - s * s * invN) * (1.f / (float)(HW - 1)) + EPSV;
    stA[tid] = sa * invN;
    stM[tid] = mean;
    stS[tid] = sqrtf(var);
  }
  {
    int o = tid >> 3, g = tid & 7;                 // 8 lanes per out-channel
    const float* wo = w_conv + o * 576 + g * 72;   // 8 in-channels x 9 taps
    float s = 0.f;
    u64 wb[9] = {0,0,0,0,0,0,0,0,0};
    #pragma unroll
    for (int i = 0; i < 8; i++) {
      #pragma unroll
      for (int tp = 0; tp < 9; tp++) {
        float v = wo[i * 9 + tp];
        s += fabsf(v);
        if (v > 0.f) wb[tp] |= (1ull << (g * 8 + i));
      }
    }
    #pragma unroll
    for (int off = 4; off > 0; off >>= 1) {
      s += __shfl_down(s, off, 8);
      #pragma unroll
      for (int tp = 0; tp < 9; tp++)
        wb[tp] |= __shfl_down(wb[tp], off, 8);
    }
    if (g == 0) {
      swv[o] = s * (1.f / 576.f);
      #pragma unroll
      for (int tp = 0; tp < 9; tp++) wsign[o * 9 + tp] = wb[tp];
    }
  }
  __syncthreads();
  int b = tid >> 6, c = tid & 63;
  float y = 0.f;
  #pragma unroll
  for (int k = 0; k < 3; k++) {
    int cc = c + k - 1;
    if (cc >= 0 && cc < 64) {
      int j = b * 64 + cc;
      y += stA[j] * w1d[0 * 3 + k] + stM[j] * w1d[1 * 3 + k] + stS[j] * w1d[2 * 3 + k];
    }
  }
  float gate = 1.f / (1.f + expf(-y));
  alpha[tid] = gate * swv[c];   // folds scale_w[o] * gate[b][o]
}

// ---------------- K3: XNOR conv, 4 px/thread, float4 I/O ----------------
// 512 blocks = b*64 + hg; block covers 4 rows (h0..h0+3), 256 threads x 4 px.
__global__ __launch_bounds__(256) void k_conv4(const u64* __restrict__ packed,
                                               const u64* __restrict__ wsign,
                                               const float* __restrict__ alpha,
                                               const float* __restrict__ x,
                                               const float* __restrict__ pr_b0,
                                               const float* __restrict__ prelu_a,
                                               const float* __restrict__ pr_b1,
                                               float* __restrict__ out) {
  int blk = blockIdx.x;
  int b = blk >> 6, hg = blk & 63;
  int h0 = hg << 2;
  int t = threadIdx.x;
  __shared__ u64 rows[6][W];          // packed rows h0-1 .. h0+4
  const u64* pb = packed + (size_t)b * H * W;
  #pragma unroll
  for (int r = 0; r < 6; ++r) {
    int hr = h0 - 1 + r;
    rows[r][t] = (hr >= 0 && hr < H) ? pb[hr * W + t] : 0ull;
  }
  __syncthreads();

  int tr = t >> 6, lane = t & 63;
  int tw = lane << 2;
  int h  = h0 + tr;
  bool rTop = (h > 0), rBot = (h < H - 1);       // wave-uniform
  u64 vm0 = (lane == 0)  ? 0ull : ~0ull;
  u64 vm5 = (lane == 63) ? 0ull : ~0ull;

  u64 nw[3][6];
  #pragma unroll
  for (int rr = 0; rr < 3; ++rr) {
    #pragma unroll
    for (int j = 0; j < 6; ++j) {
      int wi = tw - 1 + j;
      wi = (wi < 0) ? 0 : (wi > W - 1 ? W - 1 : wi);
      nw[rr][j] = rows[tr + rr][wi];
    }
  }
  int nr = 1 + (int)rTop + (int)rBot;
  float base0 = 64.f * (float)nr * ((lane == 0)  ? 2.f : 3.f);
  float base1 = 64.f * (float)nr * 3.f;
  float base3 = 64.f * (float)nr * ((lane == 63) ? 2.f : 3.f);

  size_t xoff = (size_t)b * C * HW + (size_t)h * W + tw;
  const float* al = alpha + b * 64;

  for (int o = 0; o < 64; ++o) {
    const u64* ws = wsign + o * 9;
    u64 w0=ws[0], w1=ws[1], w2=ws[2], w3=ws[3], w4=ws[4],
        w5=ws[5], w6=ws[6], w7=ws[7], w8=ws[8];
    int c0 = 0, c1 = 0, c2 = 0, c3 = 0;
    if (rTop) {
      c0 += __popcll((nw[0][0]^w0)&vm0) + __popcll(nw[0][1]^w1) + __popcll(nw[0][2]^w2);
      c1 += __popcll(nw[0][1]^w0) + __popcll(nw[0][2]^w1) + __popcll(nw[0][3]^w2);
      c2 += __popcll(nw[0][2]^w0) + __popcll(nw[0][3]^w1) + __popcll(nw[0][4]^w2);
      c3 += __popcll(nw[0][3]^w0) + __popcll(nw[0][4]^w1) + __popcll((nw[0][5]^w2)&vm5);
    }
    {
      c0 += __popcll((nw[1][0]^w3)&vm0) + __popcll(nw[1][1]^w4) + __popcll(nw[1][2]^w5);
      c1 += __popcll(nw[1][1]^w3) + __popcll(nw[1][2]^w4) + __popcll(nw[1][3]^w5);
      c2 += __popcll(nw[1][2]^w3) + __popcll(nw[1][3]^w4) + __popcll(nw[1][4]^w5);
      c3 += __popcll(nw[1][3]^w3) + __popcll(nw[1][4]^w4) + __popcll((nw[1][5]^w5)&vm5);
    }
    if (rBot) {
      c0 += __popcll((nw[2][0]^w6)&vm0) + __popcll(nw[2][1]^w7) + __popcll(nw[2][2]^w8);
      c1 += __popcll(nw[2][1]^w6) + __popcll(nw[2][2]^w7) + __popcll(nw[2][3]^w8);
      c2 += __popcll(nw[2][2]^w6) + __popcll(nw[2][3]^w7) + __popcll(nw[2][4]^w8);
      c3 += __popcll(nw[2][3]^w6) + __popcll(nw[2][4]^w7) + __popcll((nw[2][5]^w8)&vm5);
    }
    float a  = al[o];
    float b0 = pr_b0[o], pa = prelu_a[o], b1 = pr_b1[o];
    f32x4 xr = *(const f32x4*)(x + xoff + (size_t)o * HW);
    float d0 = (base0 - 2.f*(float)c0) * a + b0;
    float d1 = (base1 - 2.f*(float)c1) * a + b0;
    float d2 = (base1 - 2.f*(float)c2) * a + b0;
    float d3 = (base3 - 2.f*(float)c3) * a + b0;
    d0 = (d0 > 0.f) ? d0 : pa * d0;
    d1 = (d1 > 0.f) ? d1 : pa * d1;
    d2 = (d2 > 0.f) ? d2 : pa * d2;
    d3 = (d3 > 0.f) ? d3 : pa * d3;
    f32x4 ov;
    ov.x = d0 + b1 + xr.x;
    ov.y = d1 + b1 + xr.y;
    ov.z = d2 + b1 + xr.z;
    ov.w = d3 + b1 + xr.w;
    __builtin_nontemporal_store(ov, (f32x4*)(out + xoff + (size_t)o * HW));
  }
}

extern "C" void kernel_launch(void* const* d_in, const int* in_sizes, int n_in,
                              void* d_out, int out_size, void* d_ws, size_t ws_size,
                              hipStream_t stream) {
  const float* x       = (const float*)d_in[0];
  const float* b_move  = (const float*)d_in[1];
  const float* w_conv  = (const float*)d_in[2];
  const float* w1d     = (const float*)d_in[3];
  const float* pr_b0   = (const float*)d_in[4];
  const float* prelu_a = (const float*)d_in[5];
  const float* pr_b1   = (const float*)d_in[6];
  float* out = (float*)d_out;

  char* ws = (char*)d_ws;
  // ws: packed u64[8*256*256] = 4 MiB; sums 3*512 f32; alpha 512 f32; wsign 576 u64
  u64*   packed = (u64*)ws;
  float* sums   = (float*)(ws + 4194304);
  float* alpha  = (float*)(ws + 4194304 + 8192);
  u64*   wsign  = (u64*)(ws + 4194304 + 16384);

  k_stats<<<512, 256, 0, stream>>>(x, b_move, sums);
  k_pack<<<1024, 256, 0, stream>>>(x, b_move, packed);
  k_gate<<<1, 512, 0, stream>>>(sums, w_conv, w1d, alpha, wsign);
  k_conv4<<<512, 256, 0, stream>>>(packed, wsign, alpha, x,
                                   pr_b0, prelu_a, pr_b1, out);
}

// Round 6
// 106.223 us; speedup vs baseline: 1.3224x; 1.1345x over previous
//
#include <hip/hip_runtime.h>
#include <stdint.h>

#define BB 8
#define C  64
#define H  256
#define W  256
#define HW (H*W)
#define EPSV 1e-6f

typedef unsigned long long u64;
typedef float __attribute__((ext_vector_type(4))) f32x4;

// ---------------- K1a: per-(b,c) stats, pure streaming ----------------
// 512 blocks = one per (b,c) plane. Register accumulation, one reduce at end.
__global__ __launch_bounds__(256) void k_stats(const float* __restrict__ x,
                                               const float* __restrict__ bmove,
                                               float* __restrict__ sums /* [3][512] */) {
  int bc = blockIdx.x;
  float bm = bmove[bc & 63];
  const f32x4* p = (const f32x4*)(x + (size_t)bc * HW);
  int t = threadIdx.x;
  float s = 0.f, s2 = 0.f, sa = 0.f;
  #pragma unroll 8
  for (int k = 0; k < 64; ++k) {
    f32x4 v = p[(k << 8) | t];
    float a0 = v.x + bm, a1 = v.y + bm, a2 = v.z + bm, a3 = v.w + bm;
    s  += a0 + a1 + a2 + a3;
    s2 += a0*a0 + a1*a1 + a2*a2 + a3*a3;
    sa += fabsf(a0) + fabsf(a1) + fabsf(a2) + fabsf(a3);
  }
  #pragma unroll
  for (int off = 32; off > 0; off >>= 1) {
    s  += __shfl_down(s,  off, 64);
    s2 += __shfl_down(s2, off, 64);
    sa += __shfl_down(sa, off, 64);
  }
  __shared__ float red[4][3];
  int wid = t >> 6;
  if ((t & 63) == 0) { red[wid][0] = s; red[wid][1] = s2; red[wid][2] = sa; }
  __syncthreads();
  if (t == 0) {
    float S  = red[0][0] + red[1][0] + red[2][0] + red[3][0];
    float S2 = red[0][1] + red[1][1] + red[2][1] + red[3][1];
    float SA = red[0][2] + red[1][2] + red[2][2] + red[3][2];
    sums[bc] = S; sums[512 + bc] = S2; sums[1024 + bc] = SA;
  }
}

// ---------------- K1b: LDS-transpose + ballot sign-pack ----------------
// 1024 blocks (b = blk>>7, 2-row strip), 256 threads.  (unchanged control)
__global__ __launch_bounds__(256) void k_pack(const float* __restrict__ x,
                                              const float* __restrict__ bmove,
                                              u64* __restrict__ packed) {
  int blk = blockIdx.x;
  int b   = blk >> 7;
  int rg  = blk & 127;
  int h0  = rg << 1;
  int tid = threadIdx.x;
  int wid = tid >> 6, lane = tid & 63;
  __shared__ f32x4 lds4[64 * 33];

  float bm = bmove[lane];               // lane = channel in consume phase
  int p4l = tid & 31;
  int cg  = tid >> 5;
  const size_t bbase = (size_t)b * C * HW;

  for (int tile = 0; tile < 4; ++tile) {
    int h  = h0 + (tile >> 1);
    int wb = (tile & 1) << 7;
    __syncthreads();
    #pragma unroll
    for (int cc = 0; cc < 8; ++cc) {
      int c = cg + (cc << 3);
      lds4[c * 33 + p4l] =
          *((const f32x4*)(x + bbase + (size_t)c * HW + h * W + wb) + p4l);
    }
    __syncthreads();
    u64* pdst = packed + ((size_t)(b * H + h)) * W + wb;
    #pragma unroll
    for (int k = 0; k < 8; ++k) {
      int p4i = (wid << 3) + k;
      f32x4 v = lds4[lane * 33 + p4i];
      u64 q0 = __ballot(v.x + bm > 0.f);
      u64 q1 = __ballot(v.y + bm > 0.f);
      u64 q2 = __ballot(v.z + bm > 0.f);
      u64 q3 = __ballot(v.w + bm > 0.f);
      u64 qa = (lane & 1) ? q1 : q0;
      u64 qb = (lane & 1) ? q3 : q2;
      u64 qq = (lane & 2) ? qb : qa;
      if (lane < 4) pdst[(p4i << 2) + lane] = qq;
    }
  }
}

// ---------------- K2: gate (conv1d over C + sigmoid) + weight prep ----------
__global__ __launch_bounds__(512) void k_gate(const float* __restrict__ sums,
                                              const float* __restrict__ w_conv,
                                              const float* __restrict__ w1d,
                                              float* __restrict__ alpha,
                                              u64* __restrict__ wsign) {
  __shared__ float stA[512], stM[512], stS[512];  // [b*64 + c]
  __shared__ float swv[64];
  int tid = threadIdx.x;
  {
    float s = sums[tid], s2 = sums[512 + tid], sa = sums[1024 + tid];
    const float invN = 1.f / (float)HW;
    float mean = s * invN;
    float var  = (s2 - s * s * invN) * (1.f / (float)(HW - 1)) + EPSV;
    stA[tid] = sa * invN;
    stM[tid] = mean;
    stS[tid] = sqrtf(var);
  }
  {
    int o = tid >> 3, g = tid & 7;                 // 8 lanes per out-channel
    const float* wo = w_conv + o * 576 + g * 72;   // 8 in-channels x 9 taps
    float s = 0.f;
    u64 wb[9] = {0,0,0,0,0,0,0,0,0};
    #pragma unroll
    for (int i = 0; i < 8; i++) {
      #pragma unroll
      for (int tp = 0; tp < 9; tp++) {
        float v = wo[i * 9 + tp];
        s += fabsf(v);
        if (v > 0.f) wb[tp] |= (1ull << (g * 8 + i));
      }
    }
    #pragma unroll
    for (int off = 4; off > 0; off >>= 1) {
      s += __shfl_down(s, off, 8);
      #pragma unroll
      for (int tp = 0; tp < 9; tp++)
        wb[tp] |= __shfl_down(wb[tp], off, 8);
    }
    if (g == 0) {
      swv[o] = s * (1.f / 576.f);
      #pragma unroll
      for (int tp = 0; tp < 9; tp++) wsign[o * 9 + tp] = wb[tp];
    }
  }
  __syncthreads();
  int b = tid >> 6, c = tid & 63;
  float y = 0.f;
  #pragma unroll
  for (int k = 0; k < 3; k++) {
    int cc = c + k - 1;
    if (cc >= 0 && cc < 64) {
      int j = b * 64 + cc;
      y += stA[j] * w1d[0 * 3 + k] + stM[j] * w1d[1 * 3 + k] + stS[j] * w1d[2 * 3 + k];
    }
  }
  float gate = 1.f / (1.f + expf(-y));
  alpha[tid] = gate * swv[c];   // folds scale_w[o] * gate[b][o]
}

// ---------------- K3: XNOR conv, 4 px/thread, o-split x4 for occupancy ------
// 2048 blocks: blk = b*256 + hg*4 + oq. Block: 4-row strip, o in [oq*16, +16).
__global__ __launch_bounds__(256) void k_conv4(const u64* __restrict__ packed,
                                               const u64* __restrict__ wsign,
                                               const float* __restrict__ alpha,
                                               const float* __restrict__ x,
                                               const float* __restrict__ pr_b0,
                                               const float* __restrict__ prelu_a,
                                               const float* __restrict__ pr_b1,
                                               float* __restrict__ out) {
  int blk = blockIdx.x;
  int oq = blk & 3;
  int hg = (blk >> 2) & 63;
  int b  = blk >> 8;
  int h0 = hg << 2;
  int t = threadIdx.x;
  __shared__ u64 rows[6][W];          // packed rows h0-1 .. h0+4
  const u64* pb = packed + (size_t)b * H * W;
  #pragma unroll
  for (int r = 0; r < 6; ++r) {
    int hr = h0 - 1 + r;
    rows[r][t] = (hr >= 0 && hr < H) ? pb[hr * W + t] : 0ull;
  }
  __syncthreads();

  int tr = t >> 6, lane = t & 63;
  int tw = lane << 2;
  int h  = h0 + tr;
  bool rTop = (h > 0), rBot = (h < H - 1);       // wave-uniform
  u64 vm0 = (lane == 0)  ? 0ull : ~0ull;
  u64 vm5 = (lane == 63) ? 0ull : ~0ull;

  u64 nw[3][6];
  #pragma unroll
  for (int rr = 0; rr < 3; ++rr) {
    #pragma unroll
    for (int j = 0; j < 6; ++j) {
      int wi = tw - 1 + j;
      wi = (wi < 0) ? 0 : (wi > W - 1 ? W - 1 : wi);
      nw[rr][j] = rows[tr + rr][wi];
    }
  }
  int nr = 1 + (int)rTop + (int)rBot;
  float base0 = 64.f * (float)nr * ((lane == 0)  ? 2.f : 3.f);
  float base1 = 64.f * (float)nr * 3.f;
  float base3 = 64.f * (float)nr * ((lane == 63) ? 2.f : 3.f);

  int o0 = oq << 4;
  size_t xoff = (size_t)b * C * HW + (size_t)(o0) * HW + (size_t)h * W + tw;
  const float* al = alpha + b * 64 + o0;
  const float* pb0 = pr_b0 + o0;
  const float* ppa = prelu_a + o0;
  const float* pb1 = pr_b1 + o0;
  const u64* wsq = wsign + (size_t)o0 * 9;

  #pragma unroll 2
  for (int oo = 0; oo < 16; ++oo) {
    const u64* ws = wsq + oo * 9;
    u64 w0=ws[0], w1=ws[1], w2=ws[2], w3=ws[3], w4=ws[4],
        w5=ws[5], w6=ws[6], w7=ws[7], w8=ws[8];
    f32x4 xr = *(const f32x4*)(x + xoff + (size_t)oo * HW);
    int c0 = 0, c1 = 0, c2 = 0, c3 = 0;
    if (rTop) {
      c0 += __popcll((nw[0][0]^w0)&vm0) + __popcll(nw[0][1]^w1) + __popcll(nw[0][2]^w2);
      c1 += __popcll(nw[0][1]^w0) + __popcll(nw[0][2]^w1) + __popcll(nw[0][3]^w2);
      c2 += __popcll(nw[0][2]^w0) + __popcll(nw[0][3]^w1) + __popcll(nw[0][4]^w2);
      c3 += __popcll(nw[0][3]^w0) + __popcll(nw[0][4]^w1) + __popcll((nw[0][5]^w2)&vm5);
    }
    {
      c0 += __popcll((nw[1][0]^w3)&vm0) + __popcll(nw[1][1]^w4) + __popcll(nw[1][2]^w5);
      c1 += __popcll(nw[1][1]^w3) + __popcll(nw[1][2]^w4) + __popcll(nw[1][3]^w5);
      c2 += __popcll(nw[1][2]^w3) + __popcll(nw[1][3]^w4) + __popcll(nw[1][4]^w5);
      c3 += __popcll(nw[1][3]^w3) + __popcll(nw[1][4]^w4) + __popcll((nw[1][5]^w5)&vm5);
    }
    if (rBot) {
      c0 += __popcll((nw[2][0]^w6)&vm0) + __popcll(nw[2][1]^w7) + __popcll(nw[2][2]^w8);
      c1 += __popcll(nw[2][1]^w6) + __popcll(nw[2][2]^w7) + __popcll(nw[2][3]^w8);
      c2 += __popcll(nw[2][2]^w6) + __popcll(nw[2][3]^w7) + __popcll(nw[2][4]^w8);
      c3 += __popcll(nw[2][3]^w6) + __popcll(nw[2][4]^w7) + __popcll((nw[2][5]^w8)&vm5);
    }
    float a  = al[oo];
    float b0 = pb0[oo], pa = ppa[oo], b1 = pb1[oo];
    float d0 = (base0 - 2.f*(float)c0) * a + b0;
    float d1 = (base1 - 2.f*(float)c1) * a + b0;
    float d2 = (base1 - 2.f*(float)c2) * a + b0;
    float d3 = (base3 - 2.f*(float)c3) * a + b0;
    d0 = (d0 > 0.f) ? d0 : pa * d0;
    d1 = (d1 > 0.f) ? d1 : pa * d1;
    d2 = (d2 > 0.f) ? d2 : pa * d2;
    d3 = (d3 > 0.f) ? d3 : pa * d3;
    f32x4 ov;
    ov.x = d0 + b1 + xr.x;
    ov.y = d1 + b1 + xr.y;
    ov.z = d2 + b1 + xr.z;
    ov.w = d3 + b1 + xr.w;
    __builtin_nontemporal_store(ov, (f32x4*)(out + xoff + (size_t)oo * HW));
  }
}

extern "C" void kernel_launch(void* const* d_in, const int* in_sizes, int n_in,
                              void* d_out, int out_size, void* d_ws, size_t ws_size,
                              hipStream_t stream) {
  const float* x       = (const float*)d_in[0];
  const float* b_move  = (const float*)d_in[1];
  const float* w_conv  = (const float*)d_in[2];
  const float* w1d     = (const float*)d_in[3];
  const float* pr_b0   = (const float*)d_in[4];
  const float* prelu_a = (const float*)d_in[5];
  const float* pr_b1   = (const float*)d_in[6];
  float* out = (float*)d_out;

  char* ws = (char*)d_ws;
  // ws: packed u64[8*256*256] = 4 MiB; sums 3*512 f32; alpha 512 f32; wsign 576 u64
  u64*   packed = (u64*)ws;
  float* sums   = (float*)(ws + 4194304);
  float* alpha  = (float*)(ws + 4194304 + 8192);
  u64*   wsign  = (u64*)(ws + 4194304 + 16384);

  k_stats<<<512, 256, 0, stream>>>(x, b_move, sums);
  k_pack<<<1024, 256, 0, stream>>>(x, b_move, packed);
  k_gate<<<1, 512, 0, stream>>>(sums, w_conv, w1d, alpha, wsign);
  k_conv4<<<2048, 256, 0, stream>>>(packed, wsign, alpha, x,
                                    pr_b0, prelu_a, pr_b1, out);
}